// Round 11
// baseline (323.668 us; speedup 1.0000x reference)
//
#include <hip/hip_runtime.h>
#include <hip/hip_bf16.h>
#include <cstdint>
#include <cstddef>

#define HW     16384      // H*W
#define WIDTH  128
#define NB     2
#define NTOPK  300
#define JUNC_TH 0.008f

typedef __attribute__((ext_vector_type(8))) short s16x8;
typedef __attribute__((ext_vector_type(2))) float f32x2;
typedef __attribute__((ext_vector_type(4))) float f32x4;
typedef __attribute__((ext_vector_type(4))) int   i32x4;
typedef __attribute__((ext_vector_type(8))) int   i32x8;

// ---------------------------------------------------------------- utilities
__device__ __forceinline__ float sigm(float x) { return 1.0f / (1.0f + expf(-x)); }

__device__ __forceinline__ unsigned short f2bf(float f) {
  __hip_bfloat16 h = __float2bfloat16(f);
  return __hip_bfloat16_raw(h).x;
}
// OCP e4m3 conversion via v_cvt_pk_fp8_f32 (gfx950 HW format is OCP)
__device__ __forceinline__ unsigned char f2fp8(float v) {
  return (unsigned char)(__builtin_amdgcn_cvt_pk_fp8_f32(v, 0.0f, 0, false) & 0xff);
}
// bf16 pair (packed dword) -> f32x2, exact (shift / mask)
__device__ __forceinline__ f32x2 bfpair(unsigned int u) {
  f32x2 r;
  r[0] = __uint_as_float(u << 16);
  r[1] = __uint_as_float(u & 0xffff0000u);
  return r;
}
// packed fp32 ops forced via VOP3P asm (R8/R9-proven bit-exact vs scalar chain)
__device__ __forceinline__ f32x2 pkmul(f32x2 a, f32x2 b) {
  f32x2 d;
  asm("v_pk_mul_f32 %0, %1, %2" : "=v"(d) : "v"(a), "v"(b));
  return d;
}
__device__ __forceinline__ f32x2 pkadd(f32x2 a, f32x2 b) {
  f32x2 d;
  asm("v_pk_add_f32 %0, %1, %2" : "=v"(d) : "v"(a), "v"(b));
  return d;
}
__device__ __forceinline__ f32x2 max2(f32x2 a, f32x2 b) {
  f32x2 r;
  r[0] = fmaxf(a[0], b[0]);
  r[1] = fmaxf(a[1], b[1]);
  return r;
}

#define GLOAD_LDS16(gp, lp)                                                        \
  __builtin_amdgcn_global_load_lds((const __attribute__((address_space(1))) void*)(gp), \
                                   (__attribute__((address_space(3))) void*)(lp), 16, 0, 0)

// XCD-cohort swizzle: consecutive blocks round-robin across 8 XCDs; give each
// XCD a run of n-slices over one m-tile -> A-tile L2 reuse.
__device__ __forceinline__ void fc_tile_map(int bid, int nm, int& m_idx, int& n_idx) {
  if ((nm & 7) == 0) {
    int x = bid & 7;
    int k = bid >> 3;              // 0 .. nm*4/8-1
    m_idx = x * (nm >> 3) + (k >> 2);
    n_idx = k & 3;
  } else {
    m_idx = bid >> 2;
    n_idx = bid & 3;
  }
}

// ---------------------------------------------------------------- W transpose (256x128 <- 128x256), fp32
__global__ void k_transpose_w(const float* __restrict__ w, float* __restrict__ wt) {
  int i = blockIdx.x * 256 + threadIdx.x;   // 32768
  int d = i & 127, c = i >> 7;
  wt[c * 128 + d] = w[d * 256 + c];
}

// ---------------------------------------------------------------- FC weight transpose+cast for BOTH fc layers in one launch
// (blockIdx.z selects w1/w2; per-element work byte-identical to the old
// two-launch version — pure launch-count reduction.)
__global__ __launch_bounds__(256) void k_wtrans2(const float* __restrict__ w1,
                                                 const float* __restrict__ w2,
                                                 unsigned char* __restrict__ wt1,
                                                 unsigned char* __restrict__ wt2) {
  __shared__ float tile[32][33];
  const float* w = blockIdx.z ? w2 : w1;
  unsigned char* wt = blockIdx.z ? wt2 : wt1;
  int n0 = blockIdx.x * 32, k0 = blockIdx.y * 32;
  int tx = threadIdx.x & 31, ty = threadIdx.x >> 5;   // 32 x 8
#pragma unroll
  for (int r = 0; r < 32; r += 8)
    tile[ty + r][tx] = w[(size_t)(k0 + ty + r) * 1024 + n0 + tx];
  __syncthreads();
#pragma unroll
  for (int r = 0; r < 32; r += 8)
    wt[(size_t)(n0 + ty + r) * 1024 + k0 + tx] = f2fp8(tile[tx][ty + r]);
}

// ---------------------------------------------------------------- loi GEMM via bf16 MFMA: loi_t[b][p][d]
// R10-verified: 16x16x32 bf16 MFMA, 64p x 128d tile, 4 waves.
__global__ __launch_bounds__(256) void k_loi(const float* __restrict__ F,
                                             const float* __restrict__ wt,
                                             const float* __restrict__ bias,
                                             unsigned short* __restrict__ loi) {
  __shared__ __align__(16) unsigned short Ash[64 * 40];    // [p][c] pad 40
  __shared__ __align__(16) unsigned short Bsh[128 * 40];   // [d][c]
  int b = blockIdx.y;
  int p0 = blockIdx.x * 64;
  int t = threadIdx.x;
  int wv = t >> 6, lane = t & 63;
  int lr = lane & 15, ls = lane >> 4;
  const float* Fb = F + (size_t)b * 256 * HW;

  f32x4 acc[8];
#pragma unroll
  for (int dg = 0; dg < 8; ++dg) acc[dg] = (f32x4){0.f, 0.f, 0.f, 0.f};

  int cc = t >> 3, pg = t & 7;      // staging coords: c-lane 0..31, group 0..7

  for (int c0 = 0; c0 < 256; c0 += 32) {
    const float* fr = Fb + (size_t)(c0 + cc) * HW + p0 + pg * 8;
    float4 fa0 = *(const float4*)fr;
    float4 fa1 = *(const float4*)(fr + 4);
    const float* wr = wt + (size_t)(c0 + cc) * 128 + pg * 16;
    float4 fb0 = *(const float4*)wr;
    float4 fb1 = *(const float4*)(wr + 4);
    float4 fb2 = *(const float4*)(wr + 8);
    float4 fb3 = *(const float4*)(wr + 12);
    __syncthreads();                       // prev compute done before overwrite
    Ash[(pg * 8 + 0) * 40 + cc] = f2bf(fa0.x);
    Ash[(pg * 8 + 1) * 40 + cc] = f2bf(fa0.y);
    Ash[(pg * 8 + 2) * 40 + cc] = f2bf(fa0.z);
    Ash[(pg * 8 + 3) * 40 + cc] = f2bf(fa0.w);
    Ash[(pg * 8 + 4) * 40 + cc] = f2bf(fa1.x);
    Ash[(pg * 8 + 5) * 40 + cc] = f2bf(fa1.y);
    Ash[(pg * 8 + 6) * 40 + cc] = f2bf(fa1.z);
    Ash[(pg * 8 + 7) * 40 + cc] = f2bf(fa1.w);
    Bsh[(pg * 16 +  0) * 40 + cc] = f2bf(fb0.x);
    Bsh[(pg * 16 +  1) * 40 + cc] = f2bf(fb0.y);
    Bsh[(pg * 16 +  2) * 40 + cc] = f2bf(fb0.z);
    Bsh[(pg * 16 +  3) * 40 + cc] = f2bf(fb0.w);
    Bsh[(pg * 16 +  4) * 40 + cc] = f2bf(fb1.x);
    Bsh[(pg * 16 +  5) * 40 + cc] = f2bf(fb1.y);
    Bsh[(pg * 16 +  6) * 40 + cc] = f2bf(fb1.z);
    Bsh[(pg * 16 +  7) * 40 + cc] = f2bf(fb1.w);
    Bsh[(pg * 16 +  8) * 40 + cc] = f2bf(fb2.x);
    Bsh[(pg * 16 +  9) * 40 + cc] = f2bf(fb2.y);
    Bsh[(pg * 16 + 10) * 40 + cc] = f2bf(fb2.z);
    Bsh[(pg * 16 + 11) * 40 + cc] = f2bf(fb2.w);
    Bsh[(pg * 16 + 12) * 40 + cc] = f2bf(fb3.x);
    Bsh[(pg * 16 + 13) * 40 + cc] = f2bf(fb3.y);
    Bsh[(pg * 16 + 14) * 40 + cc] = f2bf(fb3.z);
    Bsh[(pg * 16 + 15) * 40 + cc] = f2bf(fb3.w);
    __syncthreads();
    s16x8 av = *(const s16x8*)&Ash[(wv * 16 + lr) * 40 + ls * 8];
#pragma unroll
    for (int dg = 0; dg < 8; ++dg) {
      s16x8 bv = *(const s16x8*)&Bsh[(dg * 16 + lr) * 40 + ls * 8];
      acc[dg] = __builtin_amdgcn_mfma_f32_16x16x32_bf16(av, bv, acc[dg], 0, 0, 0);
    }
  }
  // epilogue: C/D row = ls*4 + r (p), col = lr (within d-group)
#pragma unroll
  for (int dg = 0; dg < 8; ++dg) {
    int d = dg * 16 + lr;
    float bb = bias[d];
#pragma unroll
    for (int r = 0; r < 4; ++r) {
      int p = p0 + wv * 16 + ls * 4 + r;
      loi[((size_t)b * HW + p) * 128 + d] = f2bf(acc[dg][r] + bb);
    }
  }
}

// ---------------------------------------------------------------- jloc = softmax(out9[5:7])[1]
__global__ void k_jloc(const float* __restrict__ out9, float* __restrict__ jloc) {
  int i = blockIdx.x * 256 + threadIdx.x;    // NB*HW
  int b = i >> 14, p = i & (HW - 1);
  const float* base = out9 + (size_t)b * 9 * HW;
  float o5 = base[5 * HW + p], o6 = base[6 * HW + p];
  float m = fmaxf(o5, o6);
  float e5 = expf(o5 - m), e6 = expf(o6 - m);
  jloc[i] = e6 / (e5 + e6);
}

// ---------------------------------------------------------------- NMS + sortable key
__global__ void k_nmskey(const float* __restrict__ jloc, unsigned long long* __restrict__ keys) {
  int i = blockIdx.x * 256 + threadIdx.x;
  int b = i >> 14, p = i & (HW - 1);
  int y = p >> 7, x = p & 127;
  const float* J = jloc + (size_t)b * HW;
  float c = J[p];
  float m = c;
  for (int dy = -1; dy <= 1; ++dy) {
    int yy = y + dy;
    if (yy < 0 || yy > 127) continue;
    for (int dx = -1; dx <= 1; ++dx) {
      int xx = x + dx;
      if (xx < 0 || xx > 127) continue;
      m = fmaxf(m, J[yy * WIDTH + xx]);
    }
  }
  unsigned int vb = (c == m) ? __float_as_uint(c) : 0u;   // jloc > 0 always -> bits monotone
  keys[i] = ((unsigned long long)vb << 32) | (unsigned int)(~p);
}

// ---------------------------------------------------------------- top-300 per image via bitonic sort (1 block/image)
__global__ __launch_bounds__(1024) void k_topk(const unsigned long long* __restrict__ keys,
                                               const float* __restrict__ out9,
                                               float* __restrict__ jx, float* __restrict__ jy) {
  int b = blockIdx.x;
  __shared__ unsigned long long cand[4096];
  __shared__ int cnt;
  int t = threadIdx.x;
  if (t == 0) cnt = 0;
#pragma unroll
  for (int i = t; i < 4096; i += 1024) cand[i] = 0ull;
  __syncthreads();
  const unsigned long long* K = keys + (size_t)b * HW;
  for (int i = t; i < HW; i += 1024) {
    unsigned long long k = K[i];
    if ((k >> 32) != 0ull) {
      int pos = atomicAdd(&cnt, 1);
      if (pos < 4096) cand[pos] = k;
    }
  }
  __syncthreads();
  // bitonic sort, descending (keys distinct except zero-padding)
  for (int k = 2; k <= 4096; k <<= 1) {
    for (int j = k >> 1; j > 0; j >>= 1) {
#pragma unroll
      for (int idx = t; idx < 4096; idx += 1024) {
        int ixj = idx ^ j;
        if (ixj > idx) {
          unsigned long long a = cand[idx], c = cand[ixj];
          bool up = ((idx & k) == 0);
          if (up ? (a < c) : (a > c)) { cand[idx] = c; cand[ixj] = a; }
        }
      }
      __syncthreads();
    }
  }
  if (t < NTOPK) {
    const float* o7 = out9 + (size_t)b * 9 * HW + 7 * HW;
    const float* o8 = out9 + (size_t)b * 9 * HW + 8 * HW;
    unsigned long long bb = cand[t];
    unsigned int vb = (unsigned int)(bb >> 32);
    float val = __uint_as_float(vb);
    if (vb != 0u && val > JUNC_TH) {
      int p = (int)(~((unsigned int)(bb & 0xffffffffull))) & (HW - 1);
      float ox = sigm(o7[p]) - 0.5f;
      float oy = sigm(o8[p]) - 0.5f;
      jx[b * NTOPK + t] = (float)(p & 127) + ox + 0.5f;
      jy[b * NTOPK + t] = (float)(p >> 7) + oy + 0.5f;
    } else {
      jx[b * NTOPK + t] = 1000000.0f;
      jy[b * NTOPK + t] = 1000000.0f;
    }
  }
}

// ---------------------------------------------------------------- per-line argmin assignment + lines2 output
__global__ __launch_bounds__(256) void k_lines(const float* __restrict__ lp,
                                               const float* __restrict__ jx,
                                               const float* __restrict__ jy,
                                               float4* __restrict__ lines4,
                                               int* __restrict__ iskeep,
                                               float* __restrict__ out_lines) {
  int b = blockIdx.y;
  int l = blockIdx.x * 256 + threadIdx.x;
  __shared__ float jxs[NTOPK], jys[NTOPK];
  for (int i = threadIdx.x; i < NTOPK; i += 256) {
    jxs[i] = jx[b * NTOPK + i];
    jys[i] = jy[b * NTOPK + i];
  }
  __syncthreads();
  int gl = b * HW + l;
  const float* L = lp + (size_t)gl * 4;
  float x1 = L[0], y1 = L[1], x2 = L[2], y2 = L[3];
  float bd1 = 3.4e38f, bd2 = 3.4e38f;
  int i1 = 0, i2 = 0;
  for (int j = 0; j < NTOPK; ++j) {
    float ax = __fsub_rn(x1, jxs[j]);
    float ay = __fsub_rn(y1, jys[j]);
    float d1 = __fadd_rn(__fmul_rn(ax, ax), __fmul_rn(ay, ay));
    if (d1 < bd1) { bd1 = d1; i1 = j; }
    float ex = __fsub_rn(x2, jxs[j]);
    float ey = __fsub_rn(y2, jys[j]);
    float d2 = __fadd_rn(__fmul_rn(ex, ex), __fmul_rn(ey, ey));
    if (d2 < bd2) { bd2 = d2; i2 = j; }
  }
  int imin = min(i1, i2), imax = max(i1, i2);
  float sx1 = jxs[imin], sy1 = jys[imin], sx2 = jxs[imax], sy2 = jys[imax];
  lines4[gl] = make_float4(sx1, sy1, sx2, sy2);
  iskeep[gl] = (imin < imax) ? 1 : 0;
  ((float4*)out_lines)[gl] = make_float4(sx1 * 4.0f, sy1 * 4.0f, sx2 * 4.0f, sy2 * 4.0f);
}

// ---------------------------------------------------------------- bilinear sample + maxpool -> xvec fp8
// R11: 4 lines/block x 32 thr/line x 4 ch/thread (R6's structure, which
// PASSED — its 5x regression was the full 32-iter unroll: VGPR 256).
// Kept: #pragma unroll 4 (R5/R9 idiom, VGPR 36, no scratch), pk-asm chain
// (R8/R9-proven bit-exact), direct f32x2 weight reads (kills the 8
// extraction movs/pt of R9).  uint2 taps amortize soff/weight/addr
// overhead over 2x channels: ~32.5 -> ~14 instr/channel.
// Per-channel op order and fp8 pack order identical to R6/R9 (verified).
__global__ __launch_bounds__(128) void k_sample(const unsigned short* __restrict__ loi,
                                                const float4* __restrict__ lines4,
                                                unsigned char* __restrict__ xvec,
                                                int b_base, int l0, int rows_per_b) {
  __shared__ __align__(16) int   soff[4][32][4];
  __shared__ __align__(16) f32x2 swt2[4][32][4];
  int b = b_base + blockIdx.y;
  int t = threadIdx.x;
  {
    int li = t >> 5, k = t & 31;           // 128 threads = 4 lines x 32 points
    int l = l0 + blockIdx.x * 4 + li;
    float4 ln = lines4[b * HW + l];
    float tt = (float)k * (1.0f / 31.0f);
    float tc = 1.0f - tt;
    float px = ln.x * tt + ln.z * tc - 0.5f;
    float py = ln.y * tt + ln.w * tc - 0.5f;
    float px0 = fminf(fmaxf(floorf(px), 0.0f), 127.0f);
    float py0 = fminf(fmaxf(floorf(py), 0.0f), 127.0f);
    float px1 = fminf(px0 + 1.0f, 127.0f);
    float py1 = fminf(py0 + 1.0f, 127.0f);
    int ix0 = (int)px0, iy0 = (int)py0, ix1 = (int)px1, iy1 = (int)py1;
    float wy1 = __fsub_rn(py1, py), wy0 = __fsub_rn(py, py0);
    float wx1 = __fsub_rn(px1, px), wx0 = __fsub_rn(px, px0);
    soff[li][k][0] = (iy0 * WIDTH + ix0) * 128;
    soff[li][k][1] = (iy1 * WIDTH + ix0) * 128;
    soff[li][k][2] = (iy0 * WIDTH + ix1) * 128;
    soff[li][k][3] = (iy1 * WIDTH + ix1) * 128;
    float wa = __fmul_rn(wy1, wx1);   // -> r00
    float wb = __fmul_rn(wy0, wx1);   // -> r10
    float wc = __fmul_rn(wy1, wx0);   // -> r01
    float wd = __fmul_rn(wy0, wx0);   // -> r11
    swt2[li][k][0] = (f32x2){wa, wa};
    swt2[li][k][1] = (f32x2){wb, wb};
    swt2[li][k][2] = (f32x2){wc, wc};
    swt2[li][k][3] = (f32x2){wd, wd};
  }
  __syncthreads();
  int li = t >> 5, c4 = t & 31;            // channels 4*c4 .. 4*c4+3
  int l = l0 + blockIdx.x * 4 + li;
  const unsigned short* Lb = loi + (size_t)b * HW * 128 + (c4 << 2);
  f32x2 rm0 = (f32x2){-3.4e38f, -3.4e38f}, rm1 = rm0;
  f32x2 mA[8], mB[8];                      // pooled: mA = ch(0,1), mB = ch(2,3)
#pragma unroll 4
  for (int k = 0; k < 32; ++k) {
    int4  o  = *(const int4*)soff[li][k];
    f32x2 wa = swt2[li][k][0];
    f32x2 wb = swt2[li][k][1];
    f32x2 wc = swt2[li][k][2];
    f32x2 wd = swt2[li][k][3];
    uint2 u0 = *(const uint2*)(Lb + o.x);
    uint2 u1 = *(const uint2*)(Lb + o.y);
    uint2 u2 = *(const uint2*)(Lb + o.z);
    uint2 u3 = *(const uint2*)(Lb + o.w);
    // ((v0*wa + v1*wb) + v2*wc) + v3*wd — same per-channel order as R9
    f32x2 sA = pkadd(pkadd(pkadd(pkmul(bfpair(u0.x), wa), pkmul(bfpair(u1.x), wb)),
                           pkmul(bfpair(u2.x), wc)), pkmul(bfpair(u3.x), wd));
    f32x2 sB = pkadd(pkadd(pkadd(pkmul(bfpair(u0.y), wa), pkmul(bfpair(u1.y), wb)),
                           pkmul(bfpair(u2.y), wc)), pkmul(bfpair(u3.y), wd));
    rm0 = max2(rm0, sA);
    rm1 = max2(rm1, sB);
    if ((k & 3) == 3) {
      mA[k >> 2] = rm0;
      mB[k >> 2] = rm1;
      rm0 = (f32x2){-3.4e38f, -3.4e38f};
      rm1 = rm0;
    }
  }
  int4 pk0, pk1;
  int d;
  d = __builtin_amdgcn_cvt_pk_fp8_f32(mA[0][0], mA[1][0], 0, false);
  d = __builtin_amdgcn_cvt_pk_fp8_f32(mA[2][0], mA[3][0], d, true);
  pk0.x = d;
  d = __builtin_amdgcn_cvt_pk_fp8_f32(mA[4][0], mA[5][0], 0, false);
  d = __builtin_amdgcn_cvt_pk_fp8_f32(mA[6][0], mA[7][0], d, true);
  pk0.y = d;
  d = __builtin_amdgcn_cvt_pk_fp8_f32(mA[0][1], mA[1][1], 0, false);
  d = __builtin_amdgcn_cvt_pk_fp8_f32(mA[2][1], mA[3][1], d, true);
  pk0.z = d;
  d = __builtin_amdgcn_cvt_pk_fp8_f32(mA[4][1], mA[5][1], 0, false);
  d = __builtin_amdgcn_cvt_pk_fp8_f32(mA[6][1], mA[7][1], d, true);
  pk0.w = d;
  d = __builtin_amdgcn_cvt_pk_fp8_f32(mB[0][0], mB[1][0], 0, false);
  d = __builtin_amdgcn_cvt_pk_fp8_f32(mB[2][0], mB[3][0], d, true);
  pk1.x = d;
  d = __builtin_amdgcn_cvt_pk_fp8_f32(mB[4][0], mB[5][0], 0, false);
  d = __builtin_amdgcn_cvt_pk_fp8_f32(mB[6][0], mB[7][0], d, true);
  pk1.y = d;
  d = __builtin_amdgcn_cvt_pk_fp8_f32(mB[0][1], mB[1][1], 0, false);
  d = __builtin_amdgcn_cvt_pk_fp8_f32(mB[2][1], mB[3][1], d, true);
  pk1.z = d;
  d = __builtin_amdgcn_cvt_pk_fp8_f32(mB[4][1], mB[5][1], 0, false);
  d = __builtin_amdgcn_cvt_pk_fp8_f32(mB[6][1], mB[7][1], d, true);
  pk1.w = d;
  size_t xrow = (size_t)blockIdx.y * rows_per_b + (l - l0);
  unsigned char* X = xvec + xrow * 1024 + c4 * 32;
  *(int4*)X = pk0;
  *(int4*)(X + 16) = pk1;
}

// ---------------------------------------------------------------- unified FC kernel, MX-scaled fp8, unit scales
// MODE 0: fc1  (relu(A@Bt^T+bias) -> fp8 C)
// MODE 1: fc2log (relu(...)·w3 row-reduced partials -> logp)
// BM=BN=256, BK=128, 8 waves, 512 thr, 2x64KB LDS dbuf, one barrier per
// K-step, chunk swizzle c^(row&7) with inverse-swizzled global source.
// Zero local arrays in the hot path (R4 scratch post-mortem): named
// accumulators/fragments via X-macros.
#define ACC_COLS(X, mi) X(mi,0) X(mi,1) X(mi,2) X(mi,3) X(mi,4) X(mi,5) X(mi,6) X(mi,7)
#define ACC_ALL(X) ACC_COLS(X,0) ACC_COLS(X,1) ACC_COLS(X,2) ACC_COLS(X,3)
#define MXMFMA(a, b, c) \
  __builtin_amdgcn_mfma_scale_f32_16x16x128_f8f6f4(a, b, c, 0, 0, 0, 0x7f7f7f7f, 0, 0x7f7f7f7f)

__device__ __forceinline__ i32x8 ldf(const unsigned char* p, int s0, int s1) {
  i32x4 lo = *(const i32x4*)(p + s0);
  i32x4 hi = *(const i32x4*)(p + s1);
  i32x8 r;
  r[0] = lo[0]; r[1] = lo[1]; r[2] = lo[2]; r[3] = lo[3];
  r[4] = hi[0]; r[5] = hi[1]; r[6] = hi[2]; r[7] = hi[3];
  return r;
}

template <int MODE>
__global__ __launch_bounds__(512, 1) void k_fc(const unsigned char* __restrict__ A,
                                               const unsigned char* __restrict__ Bt,
                                               const float* __restrict__ bias,
                                               unsigned char* __restrict__ C,
                                               const float* __restrict__ w3,
                                               float* __restrict__ logp,
                                               int base, int nm) {
  __shared__ __align__(16) unsigned char sm[131072];
  int t = threadIdx.x, lane = t & 63, w = t >> 6;
  int wm = w & 3, wn = w >> 2;
  int lr = lane & 15, ls = lane >> 4;
  int m_idx, n_idx;
  fc_tile_map(blockIdx.x, nm, m_idx, n_idx);
  int m0 = m_idx * 256, n0 = n_idx * 256;

  // staging: thread t -> LDS slot t (linear), global row t>>3, chunk (t&7)^((t>>3)&7)
  int srow = t >> 3;
  int cst = (t & 7) ^ (srow & 7);
  const unsigned char* gA = A + (size_t)(m0 + srow) * 1024 + cst * 16;
  const unsigned char* gB = Bt + (size_t)(n0 + srow) * 1024 + cst * 16;
  unsigned char* sdst = sm + t * 16;

  // fragment read swizzle: chunks 2*ls, 2*ls+1 at slot (c ^ (lr&7))
  int s0 = ((2 * ls) ^ (lr & 7)) * 16;
  int s1 = ((2 * ls + 1) ^ (lr & 7)) * 16;
  int aoff = (wm * 64 + lr) * 128;            // A row base (bytes) in tile
  int boff = 32768 + (wn * 128 + lr) * 128;   // B row base

#define DECLC(mi, ni) f32x4 c##mi##ni = (f32x4){0.f, 0.f, 0.f, 0.f};
  ACC_ALL(DECLC)
#undef DECLC

  // prologue: stage K-tile 0 into buffer 0
#pragma unroll
  for (int q = 0; q < 4; ++q) GLOAD_LDS16(gA + (size_t)q * 65536, sdst + q * 8192);
#pragma unroll
  for (int q = 0; q < 4; ++q) GLOAD_LDS16(gB + (size_t)q * 65536, sdst + 32768 + q * 8192);
  __syncthreads();

#pragma unroll 2
  for (int it = 0; it < 8; ++it) {            // K = 8 x 128
    int cur = it & 1;
    if (it < 7) {
      int kb = (it + 1) * 128;
      unsigned char* d = sdst + (cur ^ 1) * 65536;
#pragma unroll
      for (int q = 0; q < 4; ++q) GLOAD_LDS16(gA + kb + (size_t)q * 65536, d + q * 8192);
#pragma unroll
      for (int q = 0; q < 4; ++q) GLOAD_LDS16(gB + kb + (size_t)q * 65536, d + 32768 + q * 8192);
    }
    const unsigned char* T = sm + cur * 65536;
    const unsigned char* TA = T + aoff;
    const unsigned char* TB = T + boff;
    i32x8 a0 = ldf(TA, s0, s1);
    i32x8 a1 = ldf(TA + 2048, s0, s1);
    i32x8 a2 = ldf(TA + 4096, s0, s1);
    i32x8 a3 = ldf(TA + 6144, s0, s1);
#define DO_NI(ni)                                    \
    {                                                \
      i32x8 b_ = ldf(TB + ni * 2048, s0, s1);        \
      c0##ni = MXMFMA(a0, b_, c0##ni);               \
      c1##ni = MXMFMA(a1, b_, c1##ni);               \
      c2##ni = MXMFMA(a2, b_, c2##ni);               \
      c3##ni = MXMFMA(a3, b_, c3##ni);               \
    }
    DO_NI(0) DO_NI(1) DO_NI(2) DO_NI(3) DO_NI(4) DO_NI(5) DO_NI(6) DO_NI(7)
#undef DO_NI
    __syncthreads();
  }

#define DECLBV(ni) float bv##ni = bias[n0 + wn * 128 + ni * 16 + lr];
  DECLBV(0) DECLBV(1) DECLBV(2) DECLBV(3) DECLBV(4) DECLBV(5) DECLBV(6) DECLBV(7)
#undef DECLBV

  if constexpr (MODE == 0) {
    __syncthreads();
    // epilogue image: 256 rows x 272B (69632 <= 131072)
#define EPI(mi, ni)                                                          \
    {                                                                        \
      int cl = wn * 128 + ni * 16 + lr;                                      \
      int rl = wm * 64 + mi * 16 + ls * 4;                                   \
      sm[(rl + 0) * 272 + cl] = f2fp8(fmaxf(c##mi##ni[0] + bv##ni, 0.0f));   \
      sm[(rl + 1) * 272 + cl] = f2fp8(fmaxf(c##mi##ni[1] + bv##ni, 0.0f));   \
      sm[(rl + 2) * 272 + cl] = f2fp8(fmaxf(c##mi##ni[2] + bv##ni, 0.0f));   \
      sm[(rl + 3) * 272 + cl] = f2fp8(fmaxf(c##mi##ni[3] + bv##ni, 0.0f));   \
    }
    ACC_ALL(EPI)
#undef EPI
    __syncthreads();
    // store: lane-contiguous 16B segments (16 lanes cover one 256B row)
#pragma unroll
    for (int p = 0; p < 8; ++p) {
      int row = p * 32 + (t >> 4), seg = t & 15;
      *(int4*)(C + (size_t)(m0 + row) * 1024 + n0 + seg * 16) =
          *(const int4*)(sm + row * 272 + seg * 16);
    }
  } else {
#define DECLWV(ni) float wv##ni = w3[n0 + wn * 128 + ni * 16 + lr];
    DECLWV(0) DECLWV(1) DECLWV(2) DECLWV(3) DECLWV(4) DECLWV(5) DECLWV(6) DECLWV(7)
#undef DECLWV
    f32x4 pm0 = (f32x4){0.f, 0.f, 0.f, 0.f}, pm1 = pm0, pm2 = pm0, pm3 = pm0;
    // same per-scalar order as before: ni ascending for each (mi, r)
#define RED(mi, ni)                                                   \
    {                                                                 \
      pm##mi[0] += fmaxf(c##mi##ni[0] + bv##ni, 0.0f) * wv##ni;       \
      pm##mi[1] += fmaxf(c##mi##ni[1] + bv##ni, 0.0f) * wv##ni;       \
      pm##mi[2] += fmaxf(c##mi##ni[2] + bv##ni, 0.0f) * wv##ni;       \
      pm##mi[3] += fmaxf(c##mi##ni[3] + bv##ni, 0.0f) * wv##ni;       \
    }
    ACC_ALL(RED)
#undef RED
    __syncthreads();
    float* red = (float*)sm;    // 256 rows x 2 (wn halves)
#define SHF(mi, r)                                                    \
    {                                                                 \
      float v = pm##mi[r];                                            \
      v += __shfl_xor(v, 1, 64);                                      \
      v += __shfl_xor(v, 2, 64);                                      \
      v += __shfl_xor(v, 4, 64);                                      \
      v += __shfl_xor(v, 8, 64);                                      \
      if (lr == 0) red[(wm * 64 + mi * 16 + ls * 4 + r) * 2 + wn] = v; \
    }
    SHF(0, 0) SHF(0, 1) SHF(0, 2) SHF(0, 3)
    SHF(1, 0) SHF(1, 1) SHF(1, 2) SHF(1, 3)
    SHF(2, 0) SHF(2, 1) SHF(2, 2) SHF(2, 3)
    SHF(3, 0) SHF(3, 1) SHF(3, 2) SHF(3, 3)
#undef SHF
    __syncthreads();
    if (t < 256)
      logp[(size_t)(base + m0 + t) * 4 + n_idx] = red[t * 2] + red[t * 2 + 1];
  }
}

// ---------------------------------------------------------------- final: reduce partials + sigmoid + keep
__global__ __launch_bounds__(256) void k_fin(const float* __restrict__ logp,
                                             const float* __restrict__ b3,
                                             const int* __restrict__ iskeep,
                                             float* __restrict__ oscore,
                                             float* __restrict__ okeep,
                                             int base) {
  int gl = base + blockIdx.x * 256 + threadIdx.x;
  float4 a = ((const float4*)logp)[gl];
  float s = (a.x + a.y) + (a.z + a.w);
  float sc = sigm(s + b3[0]);
  oscore[gl] = sc;
  okeep[gl] = (iskeep[gl] && sc > 0.05f) ? 1.0f : 0.0f;
}

// ================================================================ host
extern "C" void kernel_launch(void* const* d_in, const int* in_sizes, int n_in,
                              void* d_out, int out_size, void* d_ws, size_t ws_size,
                              hipStream_t stream) {
  const float* output     = (const float*)d_in[0];
  const float* features   = (const float*)d_in[1];
  const float* line_preds = (const float*)d_in[2];
  const float* conv_w     = (const float*)d_in[3];
  const float* conv_b     = (const float*)d_in[4];
  const float* w1         = (const float*)d_in[5];
  const float* b1         = (const float*)d_in[6];
  const float* w2         = (const float*)d_in[7];
  const float* b2         = (const float*)d_in[8];
  const float* w3         = (const float*)d_in[9];
  const float* b3         = (const float*)d_in[10];

  char* ws = (char*)d_ws;
  size_t off = 0;
  auto alloc = [&](size_t bytes) -> void* {
    void* p = ws + off;
    off += (bytes + 255) & ~(size_t)255;
    return p;
  };
  float* wt      = (float*)alloc((size_t)256 * 128 * 4);
  unsigned short* loi = (unsigned short*)alloc((size_t)NB * HW * 128 * 2);
  float* jloc    = (float*)alloc((size_t)NB * HW * 4);
  unsigned long long* keys = (unsigned long long*)alloc((size_t)NB * HW * 8);
  float* jx      = (float*)alloc((size_t)NB * NTOPK * 4);
  float* jy      = (float*)alloc((size_t)NB * NTOPK * 4);
  float4* lines4 = (float4*)alloc((size_t)NB * HW * 16);
  int* iskeep    = (int*)alloc((size_t)NB * HW * 4);
  float* logp    = (float*)alloc((size_t)NB * HW * 4 * 4);   // 4 partials per line
  unsigned char* w1b = (unsigned char*)alloc((size_t)1024 * 1024);   // [N][K] fp8
  unsigned char* w2b = (unsigned char*)alloc((size_t)1024 * 1024);
  size_t fixed = off;

  // pick activation size: merged (both images, M=32768) if it fits, else per-image chunks
  bool merged = (fixed + (size_t)2 * NB * HW * 1024 + 512 <= ws_size);
  int CH = 256;
  if (!merged) {
    const int cands[7] = {16384, 8192, 4096, 2048, 1024, 512, 256};
    for (int ci = 0; ci < 7; ++ci) {
      if (fixed + (size_t)2 * cands[ci] * 1024 + 512 <= ws_size) { CH = cands[ci]; break; }
    }
  }
  size_t actrows = merged ? (size_t)NB * HW : (size_t)CH;
  unsigned char* xvec = (unsigned char*)alloc(actrows * 1024);
  unsigned char* h1   = (unsigned char*)alloc(actrows * 1024);

  float* out_lines  = (float*)d_out;              // (B, L, 2, 2)
  float* out_scores = out_lines + (size_t)NB * HW * 4;
  float* out_keep   = out_scores + (size_t)NB * HW;

  k_transpose_w<<<128, 256, 0, stream>>>(conv_w, wt);
  k_wtrans2<<<dim3(32, 32, 2), 256, 0, stream>>>(w1, w2, w1b, w2b);
  k_loi<<<dim3(HW / 64, NB), 256, 0, stream>>>(features, wt, conv_b, loi);
  k_jloc<<<NB * HW / 256, 256, 0, stream>>>(output, jloc);
  k_nmskey<<<NB * HW / 256, 256, 0, stream>>>(jloc, keys);
  k_topk<<<NB, 1024, 0, stream>>>(keys, output, jx, jy);
  k_lines<<<dim3(HW / 256, NB), 256, 0, stream>>>(line_preds, jx, jy, lines4, iskeep, out_lines);

  if (merged) {
    int M = NB * HW, nm = M / 256;
    k_sample<<<dim3(HW / 4, NB), 128, 0, stream>>>(loi, lines4, xvec, 0, 0, HW);
    k_fc<0><<<nm * 4, 512, 0, stream>>>(xvec, w1b, b1, h1, nullptr, nullptr, 0, nm);
    k_fc<1><<<nm * 4, 512, 0, stream>>>(h1, w2b, b2, nullptr, w3, logp, 0, nm);
    k_fin<<<M / 256, 256, 0, stream>>>(logp, b3, iskeep, out_scores, out_keep, 0);
  } else {
    int nchunk = HW / CH, nm = CH / 256;
    for (int b = 0; b < NB; ++b) {
      for (int ci = 0; ci < nchunk; ++ci) {
        int l0 = ci * CH;
        int base = b * HW + l0;
        k_sample<<<dim3(CH / 4, 1), 128, 0, stream>>>(loi, lines4, xvec, b, l0, CH);
        k_fc<0><<<nm * 4, 512, 0, stream>>>(xvec, w1b, b1, h1, nullptr, nullptr, 0, nm);
        k_fc<1><<<nm * 4, 512, 0, stream>>>(h1, w2b, b2, nullptr, w3, logp, base, nm);
        k_fin<<<CH / 256, 256, 0, stream>>>(logp, b3, iskeep, out_scores, out_keep, base);
      }
    }
  }
}

// Round 12
// 311.857 us; speedup vs baseline: 1.0379x; 1.0379x over previous
//
#include <hip/hip_runtime.h>
#include <hip/hip_bf16.h>
#include <cstdint>
#include <cstddef>

#define HW     16384      // H*W
#define WIDTH  128
#define NB     2
#define NTOPK  300
#define JUNC_TH 0.008f

typedef __attribute__((ext_vector_type(8))) short s16x8;
typedef __attribute__((ext_vector_type(2))) float f32x2;
typedef __attribute__((ext_vector_type(4))) float f32x4;
typedef __attribute__((ext_vector_type(4))) int   i32x4;
typedef __attribute__((ext_vector_type(8))) int   i32x8;

// ---------------------------------------------------------------- utilities
__device__ __forceinline__ float sigm(float x) { return 1.0f / (1.0f + expf(-x)); }

__device__ __forceinline__ unsigned short f2bf(float f) {
  __hip_bfloat16 h = __float2bfloat16(f);
  return __hip_bfloat16_raw(h).x;
}
// OCP e4m3 conversion via v_cvt_pk_fp8_f32 (gfx950 HW format is OCP)
__device__ __forceinline__ unsigned char f2fp8(float v) {
  return (unsigned char)(__builtin_amdgcn_cvt_pk_fp8_f32(v, 0.0f, 0, false) & 0xff);
}
// bf16 pair (packed dword) -> f32x2, exact (shift / mask)
__device__ __forceinline__ f32x2 bfpair(unsigned int u) {
  f32x2 r;
  r[0] = __uint_as_float(u << 16);
  r[1] = __uint_as_float(u & 0xffff0000u);
  return r;
}
// packed fp32 ops forced via VOP3P asm (R8/R9-proven bit-exact vs scalar chain)
__device__ __forceinline__ f32x2 pkmul(f32x2 a, f32x2 b) {
  f32x2 d;
  asm("v_pk_mul_f32 %0, %1, %2" : "=v"(d) : "v"(a), "v"(b));
  return d;
}
__device__ __forceinline__ f32x2 pkadd(f32x2 a, f32x2 b) {
  f32x2 d;
  asm("v_pk_add_f32 %0, %1, %2" : "=v"(d) : "v"(a), "v"(b));
  return d;
}
__device__ __forceinline__ f32x2 max2(f32x2 a, f32x2 b) {
  f32x2 r;
  r[0] = fmaxf(a[0], b[0]);
  r[1] = fmaxf(a[1], b[1]);
  return r;
}

#define GLOAD_LDS16(gp, lp)                                                        \
  __builtin_amdgcn_global_load_lds((const __attribute__((address_space(1))) void*)(gp), \
                                   (__attribute__((address_space(3))) void*)(lp), 16, 0, 0)

// XCD-cohort swizzle: consecutive blocks round-robin across 8 XCDs; give each
// XCD a run of n-slices over one m-tile -> A-tile L2 reuse.
__device__ __forceinline__ void fc_tile_map(int bid, int nm, int& m_idx, int& n_idx) {
  if ((nm & 7) == 0) {
    int x = bid & 7;
    int k = bid >> 3;              // 0 .. nm*4/8-1
    m_idx = x * (nm >> 3) + (k >> 2);
    n_idx = k & 3;
  } else {
    m_idx = bid >> 2;
    n_idx = bid & 3;
  }
}

// ---------------------------------------------------------------- W transpose (256x128 <- 128x256), fp32
__global__ void k_transpose_w(const float* __restrict__ w, float* __restrict__ wt) {
  int i = blockIdx.x * 256 + threadIdx.x;   // 32768
  int d = i & 127, c = i >> 7;
  wt[c * 128 + d] = w[d * 256 + c];
}

// ---------------------------------------------------------------- FC weight transpose+cast for BOTH fc layers in one launch
__global__ __launch_bounds__(256) void k_wtrans2(const float* __restrict__ w1,
                                                 const float* __restrict__ w2,
                                                 unsigned char* __restrict__ wt1,
                                                 unsigned char* __restrict__ wt2) {
  __shared__ float tile[32][33];
  const float* w = blockIdx.z ? w2 : w1;
  unsigned char* wt = blockIdx.z ? wt2 : wt1;
  int n0 = blockIdx.x * 32, k0 = blockIdx.y * 32;
  int tx = threadIdx.x & 31, ty = threadIdx.x >> 5;   // 32 x 8
#pragma unroll
  for (int r = 0; r < 32; r += 8)
    tile[ty + r][tx] = w[(size_t)(k0 + ty + r) * 1024 + n0 + tx];
  __syncthreads();
#pragma unroll
  for (int r = 0; r < 32; r += 8)
    wt[(size_t)(n0 + ty + r) * 1024 + k0 + tx] = f2fp8(tile[tx][ty + r]);
}

// ---------------------------------------------------------------- loi GEMM via bf16 MFMA: loi_t[b][p][d]
// R10-verified: 16x16x32 bf16 MFMA, 64p x 128d tile, 4 waves.
__global__ __launch_bounds__(256) void k_loi(const float* __restrict__ F,
                                             const float* __restrict__ wt,
                                             const float* __restrict__ bias,
                                             unsigned short* __restrict__ loi) {
  __shared__ __align__(16) unsigned short Ash[64 * 40];    // [p][c] pad 40
  __shared__ __align__(16) unsigned short Bsh[128 * 40];   // [d][c]
  int b = blockIdx.y;
  int p0 = blockIdx.x * 64;
  int t = threadIdx.x;
  int wv = t >> 6, lane = t & 63;
  int lr = lane & 15, ls = lane >> 4;
  const float* Fb = F + (size_t)b * 256 * HW;

  f32x4 acc[8];
#pragma unroll
  for (int dg = 0; dg < 8; ++dg) acc[dg] = (f32x4){0.f, 0.f, 0.f, 0.f};

  int cc = t >> 3, pg = t & 7;      // staging coords: c-lane 0..31, group 0..7

  for (int c0 = 0; c0 < 256; c0 += 32) {
    const float* fr = Fb + (size_t)(c0 + cc) * HW + p0 + pg * 8;
    float4 fa0 = *(const float4*)fr;
    float4 fa1 = *(const float4*)(fr + 4);
    const float* wr = wt + (size_t)(c0 + cc) * 128 + pg * 16;
    float4 fb0 = *(const float4*)wr;
    float4 fb1 = *(const float4*)(wr + 4);
    float4 fb2 = *(const float4*)(wr + 8);
    float4 fb3 = *(const float4*)(wr + 12);
    __syncthreads();                       // prev compute done before overwrite
    Ash[(pg * 8 + 0) * 40 + cc] = f2bf(fa0.x);
    Ash[(pg * 8 + 1) * 40 + cc] = f2bf(fa0.y);
    Ash[(pg * 8 + 2) * 40 + cc] = f2bf(fa0.z);
    Ash[(pg * 8 + 3) * 40 + cc] = f2bf(fa0.w);
    Ash[(pg * 8 + 4) * 40 + cc] = f2bf(fa1.x);
    Ash[(pg * 8 + 5) * 40 + cc] = f2bf(fa1.y);
    Ash[(pg * 8 + 6) * 40 + cc] = f2bf(fa1.z);
    Ash[(pg * 8 + 7) * 40 + cc] = f2bf(fa1.w);
    Bsh[(pg * 16 +  0) * 40 + cc] = f2bf(fb0.x);
    Bsh[(pg * 16 +  1) * 40 + cc] = f2bf(fb0.y);
    Bsh[(pg * 16 +  2) * 40 + cc] = f2bf(fb0.z);
    Bsh[(pg * 16 +  3) * 40 + cc] = f2bf(fb0.w);
    Bsh[(pg * 16 +  4) * 40 + cc] = f2bf(fb1.x);
    Bsh[(pg * 16 +  5) * 40 + cc] = f2bf(fb1.y);
    Bsh[(pg * 16 +  6) * 40 + cc] = f2bf(fb1.z);
    Bsh[(pg * 16 +  7) * 40 + cc] = f2bf(fb1.w);
    Bsh[(pg * 16 +  8) * 40 + cc] = f2bf(fb2.x);
    Bsh[(pg * 16 +  9) * 40 + cc] = f2bf(fb2.y);
    Bsh[(pg * 16 + 10) * 40 + cc] = f2bf(fb2.z);
    Bsh[(pg * 16 + 11) * 40 + cc] = f2bf(fb2.w);
    Bsh[(pg * 16 + 12) * 40 + cc] = f2bf(fb3.x);
    Bsh[(pg * 16 + 13) * 40 + cc] = f2bf(fb3.y);
    Bsh[(pg * 16 + 14) * 40 + cc] = f2bf(fb3.z);
    Bsh[(pg * 16 + 15) * 40 + cc] = f2bf(fb3.w);
    __syncthreads();
    s16x8 av = *(const s16x8*)&Ash[(wv * 16 + lr) * 40 + ls * 8];
#pragma unroll
    for (int dg = 0; dg < 8; ++dg) {
      s16x8 bv = *(const s16x8*)&Bsh[(dg * 16 + lr) * 40 + ls * 8];
      acc[dg] = __builtin_amdgcn_mfma_f32_16x16x32_bf16(av, bv, acc[dg], 0, 0, 0);
    }
  }
  // epilogue: C/D row = ls*4 + r (p), col = lr (within d-group)
#pragma unroll
  for (int dg = 0; dg < 8; ++dg) {
    int d = dg * 16 + lr;
    float bb = bias[d];
#pragma unroll
    for (int r = 0; r < 4; ++r) {
      int p = p0 + wv * 16 + ls * 4 + r;
      loi[((size_t)b * HW + p) * 128 + d] = f2bf(acc[dg][r] + bb);
    }
  }
}

// ---------------------------------------------------------------- fused jloc softmax + 3x3 NMS + sortable key
// One block = 2 output rows; LDS strip holds 4 jloc rows (2 + halo, out-of-
// image rows = -inf so they never win the max — identical semantics to the
// old row-skip).  Softmax math op-identical to the old k_jloc.
__global__ __launch_bounds__(256) void k_nms(const float* __restrict__ out9,
                                             unsigned long long* __restrict__ keys) {
  __shared__ float J[4][WIDTH];
  int b = blockIdx.y;
  int y0 = blockIdx.x * 2;
  int t = threadIdx.x;
  const float* base = out9 + (size_t)b * 9 * HW;
#pragma unroll
  for (int q = 0; q < 2; ++q) {
    int idx = t + q * 256;        // 0..511 -> 4 rows x 128 cols
    int r = idx >> 7, x = idx & 127;
    int gy = y0 - 1 + r;
    float v = -3.4e38f;
    if (gy >= 0 && gy < 128) {
      int p = gy * WIDTH + x;
      float o5 = base[5 * HW + p], o6 = base[6 * HW + p];
      float m = fmaxf(o5, o6);
      float e5 = expf(o5 - m), e6 = expf(o6 - m);
      v = e6 / (e5 + e6);
    }
    J[r][x] = v;
  }
  __syncthreads();
  int r = t >> 7, x = t & 127;    // output row r (0/1), col x
  int y = y0 + r;
  float c = J[r + 1][x];
  float m = c;
#pragma unroll
  for (int dy = 0; dy <= 2; ++dy) {
#pragma unroll
    for (int dx = -1; dx <= 1; ++dx) {
      int xx = x + dx;
      if (xx < 0 || xx > 127) continue;
      m = fmaxf(m, J[r + dy][xx]);
    }
  }
  unsigned int vb = (c == m) ? __float_as_uint(c) : 0u;   // jloc > 0 always -> bits monotone
  int p = y * WIDTH + x;
  keys[(size_t)b * HW + p] = ((unsigned long long)vb << 32) | (unsigned int)(~p);
}

// ---------------------------------------------------------------- top-300 per image via bitonic sort (1 block/image)
__global__ __launch_bounds__(1024) void k_topk(const unsigned long long* __restrict__ keys,
                                               const float* __restrict__ out9,
                                               float* __restrict__ jx, float* __restrict__ jy) {
  int b = blockIdx.x;
  __shared__ unsigned long long cand[4096];
  __shared__ int cnt;
  int t = threadIdx.x;
  if (t == 0) cnt = 0;
#pragma unroll
  for (int i = t; i < 4096; i += 1024) cand[i] = 0ull;
  __syncthreads();
  const unsigned long long* K = keys + (size_t)b * HW;
  for (int i = t; i < HW; i += 1024) {
    unsigned long long k = K[i];
    if ((k >> 32) != 0ull) {
      int pos = atomicAdd(&cnt, 1);
      if (pos < 4096) cand[pos] = k;
    }
  }
  __syncthreads();
  // bitonic sort, descending (keys distinct except zero-padding)
  for (int k = 2; k <= 4096; k <<= 1) {
    for (int j = k >> 1; j > 0; j >>= 1) {
#pragma unroll
      for (int idx = t; idx < 4096; idx += 1024) {
        int ixj = idx ^ j;
        if (ixj > idx) {
          unsigned long long a = cand[idx], c = cand[ixj];
          bool up = ((idx & k) == 0);
          if (up ? (a < c) : (a > c)) { cand[idx] = c; cand[ixj] = a; }
        }
      }
      __syncthreads();
    }
  }
  if (t < NTOPK) {
    const float* o7 = out9 + (size_t)b * 9 * HW + 7 * HW;
    const float* o8 = out9 + (size_t)b * 9 * HW + 8 * HW;
    unsigned long long bb = cand[t];
    unsigned int vb = (unsigned int)(bb >> 32);
    float val = __uint_as_float(vb);
    if (vb != 0u && val > JUNC_TH) {
      int p = (int)(~((unsigned int)(bb & 0xffffffffull))) & (HW - 1);
      float ox = sigm(o7[p]) - 0.5f;
      float oy = sigm(o8[p]) - 0.5f;
      jx[b * NTOPK + t] = (float)(p & 127) + ox + 0.5f;
      jy[b * NTOPK + t] = (float)(p >> 7) + oy + 0.5f;
    } else {
      jx[b * NTOPK + t] = 1000000.0f;
      jy[b * NTOPK + t] = 1000000.0f;
    }
  }
}

// ---------------------------------------------------------------- per-line argmin assignment + lines2 output
__global__ __launch_bounds__(256) void k_lines(const float* __restrict__ lp,
                                               const float* __restrict__ jx,
                                               const float* __restrict__ jy,
                                               float4* __restrict__ lines4,
                                               int* __restrict__ iskeep,
                                               float* __restrict__ out_lines) {
  int b = blockIdx.y;
  int l = blockIdx.x * 256 + threadIdx.x;
  __shared__ float jxs[NTOPK], jys[NTOPK];
  for (int i = threadIdx.x; i < NTOPK; i += 256) {
    jxs[i] = jx[b * NTOPK + i];
    jys[i] = jy[b * NTOPK + i];
  }
  __syncthreads();
  int gl = b * HW + l;
  const float* L = lp + (size_t)gl * 4;
  float x1 = L[0], y1 = L[1], x2 = L[2], y2 = L[3];
  float bd1 = 3.4e38f, bd2 = 3.4e38f;
  int i1 = 0, i2 = 0;
  for (int j = 0; j < NTOPK; ++j) {
    float ax = __fsub_rn(x1, jxs[j]);
    float ay = __fsub_rn(y1, jys[j]);
    float d1 = __fadd_rn(__fmul_rn(ax, ax), __fmul_rn(ay, ay));
    if (d1 < bd1) { bd1 = d1; i1 = j; }
    float ex = __fsub_rn(x2, jxs[j]);
    float ey = __fsub_rn(y2, jys[j]);
    float d2 = __fadd_rn(__fmul_rn(ex, ex), __fmul_rn(ey, ey));
    if (d2 < bd2) { bd2 = d2; i2 = j; }
  }
  int imin = min(i1, i2), imax = max(i1, i2);
  float sx1 = jxs[imin], sy1 = jys[imin], sx2 = jxs[imax], sy2 = jys[imax];
  lines4[gl] = make_float4(sx1, sy1, sx2, sy2);
  iskeep[gl] = (imin < imax) ? 1 : 0;
  ((float4*)out_lines)[gl] = make_float4(sx1 * 4.0f, sy1 * 4.0f, sx2 * 4.0f, sy2 * 4.0f);
}

// ---------------------------------------------------------------- bilinear sample + maxpool -> xvec fp8
// FROZEN PERMANENTLY at the R5/R9 shape (2 lines/block x 64 chan-threads x
// 2 ch, unroll 4, VGPR 36): four structural attempts (R6/R7/R8/R11) all
// regressed or were neutral; ~64 µs is this kernel's empirical floor.
__global__ __launch_bounds__(128) void k_sample(const unsigned short* __restrict__ loi,
                                                const float4* __restrict__ lines4,
                                                unsigned char* __restrict__ xvec,
                                                int b_base, int l0, int rows_per_b) {
  __shared__ __align__(16) int   soff[2][32][4];
  __shared__ __align__(16) f32x2 swt2[2][32][4];
  int b = b_base + blockIdx.y;
  int t = threadIdx.x;
  if (t < 64) {
    int li = t >> 5, k = t & 31;
    int l = l0 + blockIdx.x * 2 + li;
    float4 ln = lines4[b * HW + l];
    float tt = (float)k * (1.0f / 31.0f);
    float tc = 1.0f - tt;
    float px = ln.x * tt + ln.z * tc - 0.5f;
    float py = ln.y * tt + ln.w * tc - 0.5f;
    float px0 = fminf(fmaxf(floorf(px), 0.0f), 127.0f);
    float py0 = fminf(fmaxf(floorf(py), 0.0f), 127.0f);
    float px1 = fminf(px0 + 1.0f, 127.0f);
    float py1 = fminf(py0 + 1.0f, 127.0f);
    int ix0 = (int)px0, iy0 = (int)py0, ix1 = (int)px1, iy1 = (int)py1;
    float wy1 = __fsub_rn(py1, py), wy0 = __fsub_rn(py, py0);
    float wx1 = __fsub_rn(px1, px), wx0 = __fsub_rn(px, px0);
    soff[li][k][0] = (iy0 * WIDTH + ix0) * 128;
    soff[li][k][1] = (iy1 * WIDTH + ix0) * 128;
    soff[li][k][2] = (iy0 * WIDTH + ix1) * 128;
    soff[li][k][3] = (iy1 * WIDTH + ix1) * 128;
    float wa = __fmul_rn(wy1, wx1);   // -> r00
    float wb = __fmul_rn(wy0, wx1);   // -> r10
    float wc = __fmul_rn(wy1, wx0);   // -> r01
    float wd = __fmul_rn(wy0, wx0);   // -> r11
    swt2[li][k][0] = (f32x2){wa, wa};
    swt2[li][k][1] = (f32x2){wb, wb};
    swt2[li][k][2] = (f32x2){wc, wc};
    swt2[li][k][3] = (f32x2){wd, wd};
  }
  __syncthreads();
  int li = t >> 6, c2 = t & 63;            // channels 2*c2, 2*c2+1
  int l = l0 + blockIdx.x * 2 + li;
  const unsigned short* Lb = loi + (size_t)b * HW * 128 + (c2 << 1);
  f32x2 rm = (f32x2){-3.4e38f, -3.4e38f};
  f32x2 fv2[8];                            // fv2[g][0]=ch0 pool g, [1]=ch1
#pragma unroll 4
  for (int k = 0; k < 32; ++k) {
    int4  o   = *(const int4*)soff[li][k];
    f32x4 w01 = *(const f32x4*)&swt2[li][k][0];   // (wa,wa,wb,wb)
    f32x4 w23 = *(const f32x4*)&swt2[li][k][2];   // (wc,wc,wd,wd)
    f32x2 wa; wa[0] = w01[0]; wa[1] = w01[1];
    f32x2 wb; wb[0] = w01[2]; wb[1] = w01[3];
    f32x2 wc; wc[0] = w23[0]; wc[1] = w23[1];
    f32x2 wd; wd[0] = w23[2]; wd[1] = w23[3];
    unsigned int u0 = *(const unsigned int*)(Lb + o.x);
    unsigned int u1 = *(const unsigned int*)(Lb + o.y);
    unsigned int u2 = *(const unsigned int*)(Lb + o.z);
    unsigned int u3 = *(const unsigned int*)(Lb + o.w);
    // ((v0*wa + v1*wb) + v2*wc) + v3*wd — same order as scalar chain
    f32x2 s = pkadd(pkadd(pkadd(pkmul(bfpair(u0), wa), pkmul(bfpair(u1), wb)),
                          pkmul(bfpair(u2), wc)), pkmul(bfpair(u3), wd));
    rm = max2(rm, s);
    if ((k & 3) == 3) {
      fv2[k >> 2] = rm;
      rm = (f32x2){-3.4e38f, -3.4e38f};
    }
  }
  int4 pk;
  int d;
  d = __builtin_amdgcn_cvt_pk_fp8_f32(fv2[0][0], fv2[1][0], 0, false);
  d = __builtin_amdgcn_cvt_pk_fp8_f32(fv2[2][0], fv2[3][0], d, true);
  pk.x = d;
  d = __builtin_amdgcn_cvt_pk_fp8_f32(fv2[4][0], fv2[5][0], 0, false);
  d = __builtin_amdgcn_cvt_pk_fp8_f32(fv2[6][0], fv2[7][0], d, true);
  pk.y = d;
  d = __builtin_amdgcn_cvt_pk_fp8_f32(fv2[0][1], fv2[1][1], 0, false);
  d = __builtin_amdgcn_cvt_pk_fp8_f32(fv2[2][1], fv2[3][1], d, true);
  pk.z = d;
  d = __builtin_amdgcn_cvt_pk_fp8_f32(fv2[4][1], fv2[5][1], 0, false);
  d = __builtin_amdgcn_cvt_pk_fp8_f32(fv2[6][1], fv2[7][1], d, true);
  pk.w = d;
  size_t xrow = (size_t)blockIdx.y * rows_per_b + (l - l0);
  *(int4*)(xvec + xrow * 1024 + c2 * 16) = pk;
}

// ---------------------------------------------------------------- unified FC kernel, MX-scaled fp8, unit scales
// MODE 0: fc1  (relu(A@Bt^T+bias) -> fp8 C)
// MODE 1: fc2log (relu(...)·w3 row-reduced partials -> logp)
// BM=BN=256, BK=128, 8 waves, 512 thr, 2x64KB LDS dbuf, one barrier per
// K-step, chunk swizzle c^(row&7) with inverse-swizzled global source.
// Zero local arrays in the hot path (R4 scratch post-mortem): named
// accumulators/fragments via X-macros.
#define ACC_COLS(X, mi) X(mi,0) X(mi,1) X(mi,2) X(mi,3) X(mi,4) X(mi,5) X(mi,6) X(mi,7)
#define ACC_ALL(X) ACC_COLS(X,0) ACC_COLS(X,1) ACC_COLS(X,2) ACC_COLS(X,3)
#define MXMFMA(a, b, c) \
  __builtin_amdgcn_mfma_scale_f32_16x16x128_f8f6f4(a, b, c, 0, 0, 0, 0x7f7f7f7f, 0, 0x7f7f7f7f)

__device__ __forceinline__ i32x8 ldf(const unsigned char* p, int s0, int s1) {
  i32x4 lo = *(const i32x4*)(p + s0);
  i32x4 hi = *(const i32x4*)(p + s1);
  i32x8 r;
  r[0] = lo[0]; r[1] = lo[1]; r[2] = lo[2]; r[3] = lo[3];
  r[4] = hi[0]; r[5] = hi[1]; r[6] = hi[2]; r[7] = hi[3];
  return r;
}

template <int MODE>
__global__ __launch_bounds__(512, 1) void k_fc(const unsigned char* __restrict__ A,
                                               const unsigned char* __restrict__ Bt,
                                               const float* __restrict__ bias,
                                               unsigned char* __restrict__ C,
                                               const float* __restrict__ w3,
                                               float* __restrict__ logp,
                                               int base, int nm) {
  __shared__ __align__(16) unsigned char sm[131072];
  int t = threadIdx.x, lane = t & 63, w = t >> 6;
  int wm = w & 3, wn = w >> 2;
  int lr = lane & 15, ls = lane >> 4;
  int m_idx, n_idx;
  fc_tile_map(blockIdx.x, nm, m_idx, n_idx);
  int m0 = m_idx * 256, n0 = n_idx * 256;

  // staging: thread t -> LDS slot t (linear), global row t>>3, chunk (t&7)^((t>>3)&7)
  int srow = t >> 3;
  int cst = (t & 7) ^ (srow & 7);
  const unsigned char* gA = A + (size_t)(m0 + srow) * 1024 + cst * 16;
  const unsigned char* gB = Bt + (size_t)(n0 + srow) * 1024 + cst * 16;
  unsigned char* sdst = sm + t * 16;

  // fragment read swizzle: chunks 2*ls, 2*ls+1 at slot (c ^ (lr&7))
  int s0 = ((2 * ls) ^ (lr & 7)) * 16;
  int s1 = ((2 * ls + 1) ^ (lr & 7)) * 16;
  int aoff = (wm * 64 + lr) * 128;            // A row base (bytes) in tile
  int boff = 32768 + (wn * 128 + lr) * 128;   // B row base

#define DECLC(mi, ni) f32x4 c##mi##ni = (f32x4){0.f, 0.f, 0.f, 0.f};
  ACC_ALL(DECLC)
#undef DECLC

  // prologue: stage K-tile 0 into buffer 0
#pragma unroll
  for (int q = 0; q < 4; ++q) GLOAD_LDS16(gA + (size_t)q * 65536, sdst + q * 8192);
#pragma unroll
  for (int q = 0; q < 4; ++q) GLOAD_LDS16(gB + (size_t)q * 65536, sdst + 32768 + q * 8192);
  __syncthreads();

#pragma unroll 2
  for (int it = 0; it < 8; ++it) {            // K = 8 x 128
    int cur = it & 1;
    if (it < 7) {
      int kb = (it + 1) * 128;
      unsigned char* d = sdst + (cur ^ 1) * 65536;
#pragma unroll
      for (int q = 0; q < 4; ++q) GLOAD_LDS16(gA + kb + (size_t)q * 65536, d + q * 8192);
#pragma unroll
      for (int q = 0; q < 4; ++q) GLOAD_LDS16(gB + kb + (size_t)q * 65536, d + 32768 + q * 8192);
    }
    const unsigned char* T = sm + cur * 65536;
    const unsigned char* TA = T + aoff;
    const unsigned char* TB = T + boff;
    i32x8 a0 = ldf(TA, s0, s1);
    i32x8 a1 = ldf(TA + 2048, s0, s1);
    i32x8 a2 = ldf(TA + 4096, s0, s1);
    i32x8 a3 = ldf(TA + 6144, s0, s1);
#define DO_NI(ni)                                    \
    {                                                \
      i32x8 b_ = ldf(TB + ni * 2048, s0, s1);        \
      c0##ni = MXMFMA(a0, b_, c0##ni);               \
      c1##ni = MXMFMA(a1, b_, c1##ni);               \
      c2##ni = MXMFMA(a2, b_, c2##ni);               \
      c3##ni = MXMFMA(a3, b_, c3##ni);               \
    }
    DO_NI(0) DO_NI(1) DO_NI(2) DO_NI(3) DO_NI(4) DO_NI(5) DO_NI(6) DO_NI(7)
#undef DO_NI
    __syncthreads();
  }

#define DECLBV(ni) float bv##ni = bias[n0 + wn * 128 + ni * 16 + lr];
  DECLBV(0) DECLBV(1) DECLBV(2) DECLBV(3) DECLBV(4) DECLBV(5) DECLBV(6) DECLBV(7)
#undef DECLBV

  if constexpr (MODE == 0) {
    __syncthreads();
    // epilogue image: 256 rows x 272B (69632 <= 131072)
#define EPI(mi, ni)                                                          \
    {                                                                        \
      int cl = wn * 128 + ni * 16 + lr;                                      \
      int rl = wm * 64 + mi * 16 + ls * 4;                                   \
      sm[(rl + 0) * 272 + cl] = f2fp8(fmaxf(c##mi##ni[0] + bv##ni, 0.0f));   \
      sm[(rl + 1) * 272 + cl] = f2fp8(fmaxf(c##mi##ni[1] + bv##ni, 0.0f));   \
      sm[(rl + 2) * 272 + cl] = f2fp8(fmaxf(c##mi##ni[2] + bv##ni, 0.0f));   \
      sm[(rl + 3) * 272 + cl] = f2fp8(fmaxf(c##mi##ni[3] + bv##ni, 0.0f));   \
    }
    ACC_ALL(EPI)
#undef EPI
    __syncthreads();
    // store: lane-contiguous 16B segments (16 lanes cover one 256B row)
#pragma unroll
    for (int p = 0; p < 8; ++p) {
      int row = p * 32 + (t >> 4), seg = t & 15;
      *(int4*)(C + (size_t)(m0 + row) * 1024 + n0 + seg * 16) =
          *(const int4*)(sm + row * 272 + seg * 16);
    }
  } else {
#define DECLWV(ni) float wv##ni = w3[n0 + wn * 128 + ni * 16 + lr];
    DECLWV(0) DECLWV(1) DECLWV(2) DECLWV(3) DECLWV(4) DECLWV(5) DECLWV(6) DECLWV(7)
#undef DECLWV
    f32x4 pm0 = (f32x4){0.f, 0.f, 0.f, 0.f}, pm1 = pm0, pm2 = pm0, pm3 = pm0;
    // same per-scalar order as before: ni ascending for each (mi, r)
#define RED(mi, ni)                                                   \
    {                                                                 \
      pm##mi[0] += fmaxf(c##mi##ni[0] + bv##ni, 0.0f) * wv##ni;       \
      pm##mi[1] += fmaxf(c##mi##ni[1] + bv##ni, 0.0f) * wv##ni;       \
      pm##mi[2] += fmaxf(c##mi##ni[2] + bv##ni, 0.0f) * wv##ni;       \
      pm##mi[3] += fmaxf(c##mi##ni[3] + bv##ni, 0.0f) * wv##ni;       \
    }
    ACC_ALL(RED)
#undef RED
    __syncthreads();
    float* red = (float*)sm;    // 256 rows x 2 (wn halves)
#define SHF(mi, r)                                                    \
    {                                                                 \
      float v = pm##mi[r];                                            \
      v += __shfl_xor(v, 1, 64);                                      \
      v += __shfl_xor(v, 2, 64);                                      \
      v += __shfl_xor(v, 4, 64);                                      \
      v += __shfl_xor(v, 8, 64);                                      \
      if (lr == 0) red[(wm * 64 + mi * 16 + ls * 4 + r) * 2 + wn] = v; \
    }
    SHF(0, 0) SHF(0, 1) SHF(0, 2) SHF(0, 3)
    SHF(1, 0) SHF(1, 1) SHF(1, 2) SHF(1, 3)
    SHF(2, 0) SHF(2, 1) SHF(2, 2) SHF(2, 3)
    SHF(3, 0) SHF(3, 1) SHF(3, 2) SHF(3, 3)
#undef SHF
    __syncthreads();
    if (t < 256)
      logp[(size_t)(base + m0 + t) * 4 + n_idx] = red[t * 2] + red[t * 2 + 1];
  }
}

// ---------------------------------------------------------------- final: reduce partials + sigmoid + keep
__global__ __launch_bounds__(256) void k_fin(const float* __restrict__ logp,
                                             const float* __restrict__ b3,
                                             const int* __restrict__ iskeep,
                                             float* __restrict__ oscore,
                                             float* __restrict__ okeep,
                                             int base) {
  int gl = base + blockIdx.x * 256 + threadIdx.x;
  float4 a = ((const float4*)logp)[gl];
  float s = (a.x + a.y) + (a.z + a.w);
  float sc = sigm(s + b3[0]);
  oscore[gl] = sc;
  okeep[gl] = (iskeep[gl] && sc > 0.05f) ? 1.0f : 0.0f;
}

// ================================================================ host
extern "C" void kernel_launch(void* const* d_in, const int* in_sizes, int n_in,
                              void* d_out, int out_size, void* d_ws, size_t ws_size,
                              hipStream_t stream) {
  const float* output     = (const float*)d_in[0];
  const float* features   = (const float*)d_in[1];
  const float* line_preds = (const float*)d_in[2];
  const float* conv_w     = (const float*)d_in[3];
  const float* conv_b     = (const float*)d_in[4];
  const float* w1         = (const float*)d_in[5];
  const float* b1         = (const float*)d_in[6];
  const float* w2         = (const float*)d_in[7];
  const float* b2         = (const float*)d_in[8];
  const float* w3         = (const float*)d_in[9];
  const float* b3         = (const float*)d_in[10];

  char* ws = (char*)d_ws;
  size_t off = 0;
  auto alloc = [&](size_t bytes) -> void* {
    void* p = ws + off;
    off += (bytes + 255) & ~(size_t)255;
    return p;
  };
  float* wt      = (float*)alloc((size_t)256 * 128 * 4);
  unsigned short* loi = (unsigned short*)alloc((size_t)NB * HW * 128 * 2);
  unsigned long long* keys = (unsigned long long*)alloc((size_t)NB * HW * 8);
  float* jx      = (float*)alloc((size_t)NB * NTOPK * 4);
  float* jy      = (float*)alloc((size_t)NB * NTOPK * 4);
  float4* lines4 = (float4*)alloc((size_t)NB * HW * 16);
  int* iskeep    = (int*)alloc((size_t)NB * HW * 4);
  float* logp    = (float*)alloc((size_t)NB * HW * 4 * 4);   // 4 partials per line
  unsigned char* w1b = (unsigned char*)alloc((size_t)1024 * 1024);   // [N][K] fp8
  unsigned char* w2b = (unsigned char*)alloc((size_t)1024 * 1024);
  size_t fixed = off;

  // pick activation size: merged (both images, M=32768) if it fits, else per-image chunks
  bool merged = (fixed + (size_t)2 * NB * HW * 1024 + 512 <= ws_size);
  int CH = 256;
  if (!merged) {
    const int cands[7] = {16384, 8192, 4096, 2048, 1024, 512, 256};
    for (int ci = 0; ci < 7; ++ci) {
      if (fixed + (size_t)2 * cands[ci] * 1024 + 512 <= ws_size) { CH = cands[ci]; break; }
    }
  }
  size_t actrows = merged ? (size_t)NB * HW : (size_t)CH;
  unsigned char* xvec = (unsigned char*)alloc(actrows * 1024);
  unsigned char* h1   = (unsigned char*)alloc(actrows * 1024);

  float* out_lines  = (float*)d_out;              // (B, L, 2, 2)
  float* out_scores = out_lines + (size_t)NB * HW * 4;
  float* out_keep   = out_scores + (size_t)NB * HW;

  k_transpose_w<<<128, 256, 0, stream>>>(conv_w, wt);
  k_wtrans2<<<dim3(32, 32, 2), 256, 0, stream>>>(w1, w2, w1b, w2b);
  k_loi<<<dim3(HW / 64, NB), 256, 0, stream>>>(features, wt, conv_b, loi);
  k_nms<<<dim3(64, NB), 256, 0, stream>>>(output, keys);
  k_topk<<<NB, 1024, 0, stream>>>(keys, output, jx, jy);
  k_lines<<<dim3(HW / 256, NB), 256, 0, stream>>>(line_preds, jx, jy, lines4, iskeep, out_lines);

  if (merged) {
    int M = NB * HW, nm = M / 256;
    k_sample<<<dim3(HW / 2, NB), 128, 0, stream>>>(loi, lines4, xvec, 0, 0, HW);
    k_fc<0><<<nm * 4, 512, 0, stream>>>(xvec, w1b, b1, h1, nullptr, nullptr, 0, nm);
    k_fc<1><<<nm * 4, 512, 0, stream>>>(h1, w2b, b2, nullptr, w3, logp, 0, nm);
    k_fin<<<M / 256, 256, 0, stream>>>(logp, b3, iskeep, out_scores, out_keep, 0);
  } else {
    int nchunk = HW / CH, nm = CH / 256;
    for (int b = 0; b < NB; ++b) {
      for (int ci = 0; ci < nchunk; ++ci) {
        int l0 = ci * CH;
        int base = b * HW + l0;
        k_sample<<<dim3(CH / 2, 1), 128, 0, stream>>>(loi, lines4, xvec, b, l0, CH);
        k_fc<0><<<nm * 4, 512, 0, stream>>>(xvec, w1b, b1, h1, nullptr, nullptr, 0, nm);
        k_fc<1><<<nm * 4, 512, 0, stream>>>(h1, w2b, b2, nullptr, w3, logp, base, nm);
        k_fin<<<CH / 256, 256, 0, stream>>>(logp, b3, iskeep, out_scores, out_keep, base);
      }
    }
  }
}